// Round 1
// baseline (510.975 us; speedup 1.0000x reference)
//
#include <hip/hip_runtime.h>
#include <math.h>

// Problem constants
#define BB    128
#define TT    32
#define DD    1024
#define NADA  1024
#define NINT  1024
#define NRANK 8
#define LNEPS 1e-5f

// ---------------------------------------------------------------------------
// Kernel 1: LayerNorm over ada_emb rows (128 rows x 1024)
// ---------------------------------------------------------------------------
__global__ __launch_bounds__(256) void ln_kernel(
    const float* __restrict__ ada, const float* __restrict__ g,
    const float* __restrict__ beta, float* __restrict__ ae)
{
    const int b = blockIdx.x;
    const float* row = ada + (size_t)b * NADA;
    float sum = 0.f, sumsq = 0.f;
    for (int i = threadIdx.x; i < NADA; i += 256) {
        float v = row[i];
        sum += v; sumsq += v * v;
    }
    // wave64 butterfly
    #pragma unroll
    for (int off = 32; off > 0; off >>= 1) {
        sum   += __shfl_down(sum, off);
        sumsq += __shfl_down(sumsq, off);
    }
    __shared__ float s1[4], s2[4];
    const int wid = threadIdx.x >> 6, lane = threadIdx.x & 63;
    if (lane == 0) { s1[wid] = sum; s2[wid] = sumsq; }
    __syncthreads();
    if (threadIdx.x == 0) {
        float a = 0.f, c = 0.f;
        for (int i = 0; i < 4; ++i) { a += s1[i]; c += s2[i]; }
        s1[0] = a; s2[0] = c;
    }
    __syncthreads();
    const float mu  = s1[0] * (1.f / NADA);
    const float var = s2[0] * (1.f / NADA) - mu * mu;
    const float inv = rsqrtf(var + LNEPS);
    for (int i = threadIdx.x; i < NADA; i += 256) {
        ae[(size_t)b * NADA + i] = (row[i] - mu) * inv * g[i] + beta[i];
    }
}

// ---------------------------------------------------------------------------
// Kernel 2: 64x64-tile GEMM with bias + exact GELU epilogue (for ae@w1)
// C(MxN) = gelu(A(MxK) @ B(KxN) + bias)
// ---------------------------------------------------------------------------
__global__ __launch_bounds__(256) void gemm64_gelu(
    const float* __restrict__ A, const float* __restrict__ Bm,
    const float* __restrict__ bias, float* __restrict__ C,
    int M, int N, int K)
{
    __shared__ float As[16][68];  // stride 68 floats = 272 B -> 16B aligned rows
    __shared__ float Bs[16][68];
    const int bm = blockIdx.y * 64;
    const int bn = blockIdx.x * 64;
    const int tid = threadIdx.x;
    const int tx = tid & 15, ty = tid >> 4;

    float acc[4][4] = {};

    const int alr = tid >> 2;          // 0..63
    const int alc = (tid & 3) << 2;    // 0,4,8,12
    const int blr = tid >> 4;          // 0..15
    const int blc = (tid & 15) << 2;   // 0..60

    for (int k0 = 0; k0 < K; k0 += 16) {
        float4 av = *(const float4*)(A + (size_t)(bm + alr) * K + k0 + alc);
        As[alc + 0][alr] = av.x;
        As[alc + 1][alr] = av.y;
        As[alc + 2][alr] = av.z;
        As[alc + 3][alr] = av.w;
        float4 bv = *(const float4*)(Bm + (size_t)(k0 + blr) * N + bn + blc);
        *(float4*)&Bs[blr][blc] = bv;
        __syncthreads();
        #pragma unroll
        for (int k = 0; k < 16; ++k) {
            float4 a = *(const float4*)&As[k][ty * 4];
            float4 b = *(const float4*)&Bs[k][tx * 4];
            float ar[4] = {a.x, a.y, a.z, a.w};
            float br[4] = {b.x, b.y, b.z, b.w};
            #pragma unroll
            for (int i = 0; i < 4; ++i)
                #pragma unroll
                for (int j = 0; j < 4; ++j)
                    acc[i][j] += ar[i] * br[j];
        }
        __syncthreads();
    }
    #pragma unroll
    for (int i = 0; i < 4; ++i) {
        const int m = bm + ty * 4 + i;
        #pragma unroll
        for (int j = 0; j < 4; ++j) {
            const int n = bn + tx * 4 + j;
            float v = acc[i][j] + bias[n];
            v = 0.5f * v * (1.f + erff(v * 0.70710678118654752f));  // exact GELU
            C[(size_t)m * N + n] = v;
        }
    }
}

// ---------------------------------------------------------------------------
// Kernels 3 & 5: 128x128-tile GEMM, 8x8 microtile.
// EPI==1: C = A@B + bias                     (h @ w2 + b2)
// EPI==2: C = A@B + A_resid + rank8 LoRA     (x @ base + x + t @ x_b^T)
// ---------------------------------------------------------------------------
template <int EPI>
__global__ __launch_bounds__(256) void gemm128(
    const float* __restrict__ A, const float* __restrict__ Bm,
    const float* __restrict__ bias, float* __restrict__ C,
    int M, int N, int K,
    const float* __restrict__ tmat, const float* __restrict__ xw)
{
    __shared__ float As[16][132];  // stride 132 floats = 528 B -> 16B aligned
    __shared__ float Bs[16][132];
    const int bm = blockIdx.y * 128;
    const int bn = blockIdx.x * 128;
    const int tid = threadIdx.x;
    const int tx = tid & 15, ty = tid >> 4;

    float acc[8][8] = {};

    const int alr = tid >> 1;          // 0..127
    const int alc = (tid & 1) * 8;     // 0 or 8
    const int blr = tid >> 4;          // 0..15
    const int blc = (tid & 15) * 8;    // 0..120

    const float* Aptr = A + (size_t)(bm + alr) * K + alc;
    const float* Bptr = Bm + (size_t)blr * N + bn + blc;

    for (int k0 = 0; k0 < K; k0 += 16) {
        float4 a0 = *(const float4*)(Aptr + k0);
        float4 a1 = *(const float4*)(Aptr + k0 + 4);
        float4 b0 = *(const float4*)(Bptr + (size_t)k0 * N);
        float4 b1 = *(const float4*)(Bptr + (size_t)k0 * N + 4);
        As[alc + 0][alr] = a0.x;
        As[alc + 1][alr] = a0.y;
        As[alc + 2][alr] = a0.z;
        As[alc + 3][alr] = a0.w;
        As[alc + 4][alr] = a1.x;
        As[alc + 5][alr] = a1.y;
        As[alc + 6][alr] = a1.z;
        As[alc + 7][alr] = a1.w;
        *(float4*)&Bs[blr][blc]     = b0;
        *(float4*)&Bs[blr][blc + 4] = b1;
        __syncthreads();
        #pragma unroll
        for (int k = 0; k < 16; ++k) {
            float4 av0 = *(const float4*)&As[k][ty * 4];
            float4 av1 = *(const float4*)&As[k][64 + ty * 4];
            float4 bv0 = *(const float4*)&Bs[k][tx * 4];
            float4 bv1 = *(const float4*)&Bs[k][64 + tx * 4];
            float ar[8] = {av0.x, av0.y, av0.z, av0.w, av1.x, av1.y, av1.z, av1.w};
            float br[8] = {bv0.x, bv0.y, bv0.z, bv0.w, bv1.x, bv1.y, bv1.z, bv1.w};
            #pragma unroll
            for (int i = 0; i < 8; ++i)
                #pragma unroll
                for (int j = 0; j < 8; ++j)
                    acc[i][j] += ar[i] * br[j];
        }
        __syncthreads();
    }

    #pragma unroll
    for (int i = 0; i < 8; ++i) {
        const int m = bm + ((i < 4) ? (ty * 4 + i) : (64 + ty * 4 + (i - 4)));
        float t8[NRANK];
        if (EPI == 2) {
            #pragma unroll
            for (int r = 0; r < NRANK; ++r) t8[r] = tmat[(size_t)m * NRANK + r];
        }
        #pragma unroll
        for (int j = 0; j < 8; ++j) {
            const int n = bn + ((j < 4) ? (tx * 4 + j) : (64 + tx * 4 + (j - 4)));
            float v = acc[i][j];
            if (EPI == 1) {
                v += bias[n];
            } else {
                // residual (A is x, K == N_out == 1024 here)
                v += A[(size_t)m * K + n];
                const int b = m >> 5;
                const float* xb = xw + (size_t)b * (2 * DD * NRANK) + DD * NRANK + (size_t)n * NRANK;
                #pragma unroll
                for (int r = 0; r < NRANK; ++r) v += t8[r] * xb[r];
            }
            C[(size_t)m * N + n] = v;
        }
    }
}

// ---------------------------------------------------------------------------
// Kernel 4: t[b,m,r] = sum_c x[b,m,c] * x_a[b,c,r]   (one block per sample b)
// ---------------------------------------------------------------------------
__global__ __launch_bounds__(256) void tmat_kernel(
    const float* __restrict__ x, const float* __restrict__ xw,
    float* __restrict__ tmat)
{
    __shared__ float xa[DD * NRANK];  // 32 KB: x_a[b] laid out [c][r]
    const int b = blockIdx.x;
    const float* src = xw + (size_t)b * (2 * DD * NRANK);  // first half = x_a
    for (int i = threadIdx.x; i < DD * NRANK; i += 256) xa[i] = src[i];
    __syncthreads();
    const int m = threadIdx.x >> 3;   // 0..31 token
    const int r = threadIdx.x & 7;    // 0..7 rank
    const float* xrow = x + ((size_t)b * TT + m) * DD;
    float accv = 0.f;
    for (int c = 0; c < DD; c += 4) {
        float4 xr = *(const float4*)(xrow + c);
        accv += xr.x * xa[(c + 0) * NRANK + r];
        accv += xr.y * xa[(c + 1) * NRANK + r];
        accv += xr.z * xa[(c + 2) * NRANK + r];
        accv += xr.w * xa[(c + 3) * NRANK + r];
    }
    tmat[((size_t)b * TT + m) * NRANK + r] = accv;
}

// ---------------------------------------------------------------------------
extern "C" void kernel_launch(void* const* d_in, const int* in_sizes, int n_in,
                              void* d_out, int out_size, void* d_ws, size_t ws_size,
                              hipStream_t stream)
{
    const float* x    = (const float*)d_in[0];  // (128,32,1024)
    const float* ada  = (const float*)d_in[1];  // (128,1024)
    const float* base = (const float*)d_in[2];  // (1024,1024)
    const float* w1   = (const float*)d_in[3];  // (1024,1024)
    const float* b1   = (const float*)d_in[4];  // (1024,)
    const float* w2   = (const float*)d_in[5];  // (1024,16384)
    const float* b2   = (const float*)d_in[6];  // (16384,)
    const float* lng  = (const float*)d_in[7];  // (1024,)
    const float* lnb  = (const float*)d_in[8];  // (1024,)
    float* out = (float*)d_out;

    float* ws = (float*)d_ws;
    float* ae = ws;                                 // 128*1024
    float* h  = ae + (size_t)BB * NADA;             // 128*1024
    float* xw = h + (size_t)BB * NINT;              // 128*16384
    float* tm = xw + (size_t)BB * 2 * DD * NRANK;   // 128*32*8

    // 1. layernorm
    ln_kernel<<<BB, 256, 0, stream>>>(ada, lng, lnb, ae);
    // 2. h = gelu(ae@w1 + b1): M=128,N=1024,K=1024
    gemm64_gelu<<<dim3(NINT / 64, BB / 64), 256, 0, stream>>>(ae, w1, b1, h, BB, NINT, NADA);
    // 3. xw = h@w2 + b2: M=128,N=16384,K=1024
    gemm128<1><<<dim3(2 * DD * NRANK / 128, 1), 256, 0, stream>>>(
        h, w2, b2, xw, BB, 2 * DD * NRANK, NINT, nullptr, nullptr);
    // 4. t = per-sample x@x_a: (128 blocks)
    tmat_kernel<<<BB, 256, 0, stream>>>(x, xw, tm);
    // 5. out = x@base + x + t@x_b^T: M=4096,N=1024,K=1024
    gemm128<2><<<dim3(DD / 128, BB * TT / 128), 256, 0, stream>>>(
        x, base, nullptr, out, BB * TT, DD, DD, tm, xw);
}

// Round 2
// 228.765 us; speedup vs baseline: 2.2336x; 2.2336x over previous
//
#include <hip/hip_runtime.h>
#include <hip/hip_bf16.h>
#include <math.h>

// Problem constants
#define BB    128
#define TT    32
#define DD    1024
#define NADA  1024
#define NINT  1024
#define NRANK 8
#define LNEPS 1e-5f
#define SPLITS 8

using bf16x8 = __attribute__((ext_vector_type(8))) short;
using f32x4  = __attribute__((ext_vector_type(4))) float;

__device__ inline short f2bf(float f) {
    __hip_bfloat16 h = __float2bfloat16(f);  // RNE
    return *reinterpret_cast<short*>(&h);
}

// ---------------------------------------------------------------------------
// Kernel 1: LayerNorm over ada_emb rows (128 rows x 1024)
// ---------------------------------------------------------------------------
__global__ __launch_bounds__(256) void ln_kernel(
    const float* __restrict__ ada, const float* __restrict__ g,
    const float* __restrict__ beta, float* __restrict__ ae)
{
    const int b = blockIdx.x;
    const float* row = ada + (size_t)b * NADA;
    float sum = 0.f, sumsq = 0.f;
    for (int i = threadIdx.x; i < NADA; i += 256) {
        float v = row[i];
        sum += v; sumsq += v * v;
    }
    #pragma unroll
    for (int off = 32; off > 0; off >>= 1) {
        sum   += __shfl_down(sum, off);
        sumsq += __shfl_down(sumsq, off);
    }
    __shared__ float s1[4], s2[4];
    const int wid = threadIdx.x >> 6, lane = threadIdx.x & 63;
    if (lane == 0) { s1[wid] = sum; s2[wid] = sumsq; }
    __syncthreads();
    if (threadIdx.x == 0) {
        float a = 0.f, c = 0.f;
        for (int i = 0; i < 4; ++i) { a += s1[i]; c += s2[i]; }
        s1[0] = a; s2[0] = c;
    }
    __syncthreads();
    const float mu  = s1[0] * (1.f / NADA);
    const float var = s2[0] * (1.f / NADA) - mu * mu;
    const float inv = rsqrtf(var + LNEPS);
    for (int i = threadIdx.x; i < NADA; i += 256) {
        ae[(size_t)b * NADA + i] = (row[i] - mu) * inv * g[i] + beta[i];
    }
}

// ---------------------------------------------------------------------------
// MFMA bf16 GEMM template. C = A(MxK) @ B(KxN), A/B fp32 in global, converted
// to bf16 during LDS staging. 256 threads, 4 waves in 2x2 arrangement.
// EPI==0: store raw partial to Cp[blockIdx.z][M][N]          (split-K gemm1)
// EPI==1: C = acc + bias                                     (h @ w2 + b2)
// EPI==2: C = acc + residual(A) + rank-8 LoRA                (x@base + x + t@x_b^T)
// ---------------------------------------------------------------------------
template <int BM, int BN, int EPI>
__global__ __launch_bounds__(256) void mfma_gemm(
    const float* __restrict__ A, const float* __restrict__ Bm,
    const float* __restrict__ bias, float* __restrict__ C,
    int M, int N, int K, int kLen,
    const float* __restrict__ tmat, const float* __restrict__ xw)
{
    constexpr int MT  = BM / 32;        // m-tiles per wave (wave covers BM/2)
    constexpr int NT  = BN / 32;        // n-tiles per wave
    constexpr int LA  = BM / 32;        // float4 A-loads per thread per k-step
    constexpr int KPT = 32 * BN / 256;  // B k-elems per thread per k-step

    __shared__ __align__(16) short As[BM][40];  // [m][k], stride 80B (16B-aligned rows)
    __shared__ __align__(16) short Bs[BN][40];  // [n][k] (transposed)

    const int bm = blockIdx.y * BM;
    const int bn = blockIdx.x * BN;
    const int kStart = blockIdx.z * kLen;
    const int tid = threadIdx.x;
    const int wave = tid >> 6, lane = tid & 63;
    const int wm0 = (wave >> 1) * (BM / 2);
    const int wn0 = (wave & 1) * (BN / 2);
    const int quad = lane >> 4, r16 = lane & 15;

    // B staging assignment: thread -> column nn, k-range [kb, kb+KPT)
    const int nn = tid % BN;
    const int kb = (tid / BN) * KPT;

    f32x4 acc[MT][NT] = {};

    for (int kt = 0; kt < kLen; kt += 32) {
        const int k0 = kStart + kt;
        // ---- stage A tile (BM x 32) as bf16, row-major [m][k]
        #pragma unroll
        for (int s = 0; s < LA; ++s) {
            const int idx = s * 256 + tid;
            const int row = idx >> 3, kc = (idx & 7) * 4;
            float4 v = *(const float4*)(A + (size_t)(bm + row) * K + k0 + kc);
            short4 p;
            p.x = f2bf(v.x); p.y = f2bf(v.y); p.z = f2bf(v.z); p.w = f2bf(v.w);
            *reinterpret_cast<short4*>(&As[row][kc]) = p;
        }
        // ---- stage B tile (32 x BN) as bf16, transposed [n][k]
        #pragma unroll
        for (int p = 0; p < KPT / 2; ++p) {
            const int k = kb + 2 * p;
            float f0 = Bm[(size_t)(k0 + k) * N + bn + nn];
            float f1 = Bm[(size_t)(k0 + k + 1) * N + bn + nn];
            unsigned int u = (unsigned int)(unsigned short)f2bf(f0) |
                             ((unsigned int)(unsigned short)f2bf(f1) << 16);
            *reinterpret_cast<unsigned int*>(&Bs[nn][k]) = u;
        }
        __syncthreads();
        // ---- fragments + MFMA
        bf16x8 af[MT], bfr[NT];
        #pragma unroll
        for (int i = 0; i < MT; ++i)
            af[i] = *reinterpret_cast<const bf16x8*>(&As[wm0 + i * 16 + r16][quad * 8]);
        #pragma unroll
        for (int j = 0; j < NT; ++j)
            bfr[j] = *reinterpret_cast<const bf16x8*>(&Bs[wn0 + j * 16 + r16][quad * 8]);
        #pragma unroll
        for (int i = 0; i < MT; ++i)
            #pragma unroll
            for (int j = 0; j < NT; ++j)
                acc[i][j] = __builtin_amdgcn_mfma_f32_16x16x32_bf16(
                    af[i], bfr[j], acc[i][j], 0, 0, 0);
        __syncthreads();
    }

    // ---- epilogue. D layout: col = lane&15, row = quad*4 + reg  (m89/m91)
    #pragma unroll
    for (int i = 0; i < MT; ++i) {
        #pragma unroll
        for (int r = 0; r < 4; ++r) {
            const int m = bm + wm0 + i * 16 + quad * 4 + r;
            float t8[NRANK];
            if (EPI == 2) {
                float4 t0 = *(const float4*)(tmat + (size_t)m * NRANK);
                float4 t1 = *(const float4*)(tmat + (size_t)m * NRANK + 4);
                t8[0] = t0.x; t8[1] = t0.y; t8[2] = t0.z; t8[3] = t0.w;
                t8[4] = t1.x; t8[5] = t1.y; t8[6] = t1.z; t8[7] = t1.w;
            }
            #pragma unroll
            for (int j = 0; j < NT; ++j) {
                const int n = bn + wn0 + j * 16 + r16;
                float v = acc[i][j][r];
                if (EPI == 0) {
                    C[((size_t)blockIdx.z * M + m) * N + n] = v;
                } else if (EPI == 1) {
                    C[(size_t)m * N + n] = v + bias[n];
                } else {
                    v += A[(size_t)m * K + n];  // residual: A is x, K == N here
                    const int b = m >> 5;
                    const float* xb = xw + (size_t)b * (2 * DD * NRANK) + DD * NRANK
                                         + (size_t)n * NRANK;
                    float4 x0 = *(const float4*)xb;
                    float4 x1 = *(const float4*)(xb + 4);
                    v += t8[0] * x0.x + t8[1] * x0.y + t8[2] * x0.z + t8[3] * x0.w
                       + t8[4] * x1.x + t8[5] * x1.y + t8[6] * x1.z + t8[7] * x1.w;
                    C[(size_t)m * N + n] = v;
                }
            }
        }
    }
}

// ---------------------------------------------------------------------------
// Combine split-K partials + bias + exact GELU -> h
// ---------------------------------------------------------------------------
__global__ __launch_bounds__(256) void combine_gelu(
    const float* __restrict__ part, const float* __restrict__ b1,
    float* __restrict__ h)
{
    const int idx = blockIdx.x * 256 + threadIdx.x;  // < 128*1024
    float s = b1[idx & (NINT - 1)];
    #pragma unroll
    for (int z = 0; z < SPLITS; ++z) s += part[(size_t)z * BB * NINT + idx];
    s = 0.5f * s * (1.f + erff(s * 0.70710678118654752f));
    h[idx] = s;
}

// ---------------------------------------------------------------------------
// t[b,m,r] = sum_c x[b,m,c] * x_a[b,c,r]   (one block per sample b)
// ---------------------------------------------------------------------------
__global__ __launch_bounds__(256) void tmat_kernel(
    const float* __restrict__ x, const float* __restrict__ xw,
    float* __restrict__ tmat)
{
    __shared__ float xa[DD * NRANK];  // 32 KB
    const int b = blockIdx.x;
    const float* src = xw + (size_t)b * (2 * DD * NRANK);  // first half = x_a
    for (int i = threadIdx.x; i < DD * NRANK; i += 256) xa[i] = src[i];
    __syncthreads();
    const int m = threadIdx.x >> 3;
    const int r = threadIdx.x & 7;
    const float* xrow = x + ((size_t)b * TT + m) * DD;
    float accv = 0.f;
    for (int c = 0; c < DD; c += 4) {
        float4 xr = *(const float4*)(xrow + c);
        accv += xr.x * xa[(c + 0) * NRANK + r];
        accv += xr.y * xa[(c + 1) * NRANK + r];
        accv += xr.z * xa[(c + 2) * NRANK + r];
        accv += xr.w * xa[(c + 3) * NRANK + r];
    }
    tmat[((size_t)b * TT + m) * NRANK + r] = accv;
}

// ---------------------------------------------------------------------------
extern "C" void kernel_launch(void* const* d_in, const int* in_sizes, int n_in,
                              void* d_out, int out_size, void* d_ws, size_t ws_size,
                              hipStream_t stream)
{
    const float* x    = (const float*)d_in[0];  // (128,32,1024)
    const float* ada  = (const float*)d_in[1];  // (128,1024)
    const float* base = (const float*)d_in[2];  // (1024,1024)
    const float* w1   = (const float*)d_in[3];  // (1024,1024)
    const float* b1   = (const float*)d_in[4];  // (1024,)
    const float* w2   = (const float*)d_in[5];  // (1024,16384)
    const float* b2   = (const float*)d_in[6];  // (16384,)
    const float* lng  = (const float*)d_in[7];  // (1024,)
    const float* lnb  = (const float*)d_in[8];  // (1024,)
    float* out = (float*)d_out;

    float* ws = (float*)d_ws;
    float* ae = ws;                               // 128*1024
    float* h  = ae + (size_t)BB * NADA;           // 128*1024
    float* xw = h + (size_t)BB * NINT;            // 128*16384 (8 MB)
    float* tm = xw + (size_t)BB * 2 * DD * NRANK; // 128*32*8
    float* part = xw;                             // alias: partials dead before xw written

    // 1. layernorm
    ln_kernel<<<BB, 256, 0, stream>>>(ada, lng, lnb, ae);
    // 2a. split-K partials of ae@w1: M=128,N=1024,K=1024, 8 splits of 128
    mfma_gemm<128, 64, 0><<<dim3(NINT / 64, 1, SPLITS), 256, 0, stream>>>(
        ae, w1, nullptr, part, BB, NINT, NADA, NADA / SPLITS, nullptr, nullptr);
    // 2b. h = gelu(sum + b1)
    combine_gelu<<<BB * NINT / 256, 256, 0, stream>>>(part, b1, h);
    // 3. xw = h@w2 + b2: M=128,N=16384,K=1024
    mfma_gemm<128, 64, 1><<<dim3(2 * DD * NRANK / 64, 1, 1), 256, 0, stream>>>(
        h, w2, b2, xw, BB, 2 * DD * NRANK, NINT, NINT, nullptr, nullptr);
    // 4. t = per-sample x@x_a
    tmat_kernel<<<BB, 256, 0, stream>>>(x, xw, tm);
    // 5. out = x@base + x + t@x_b^T: M=4096,N=1024,K=1024
    mfma_gemm<128, 64, 2><<<dim3(DD / 64, BB * TT / 128, 1), 256, 0, stream>>>(
        x, base, nullptr, out, BB * TT, DD, DD, DD, tm, xw);
}